// Round 2
// baseline (3896.440 us; speedup 1.0000x reference)
//
#include <hip/hip_runtime.h>
#include <hip/hip_bf16.h>
#include <math.h>

#define G_ 32
#define H_ 12
#define D_ 768
#define HD_ 64
#define FF_ 3072
#define B_ 2
#define T_ 2048
#define SPAN_ 63
#define SPANC_ 129
#define EPSF 1e-5f

// ---------------- LayerNorm: one wave per row ----------------
__global__ __launch_bounds__(256) void ln_kernel(const float* __restrict__ x,
                                                 const float* __restrict__ w,
                                                 const float* __restrict__ b,
                                                 float* __restrict__ out) {
    int wv = threadIdx.x >> 6;
    int lane = threadIdx.x & 63;
    int rowi = blockIdx.x * 4 + wv;
    const float* xr = x + (size_t)rowi * D_;
    float vals[12];
    float s = 0.f;
#pragma unroll
    for (int i = 0; i < 12; ++i) { vals[i] = xr[lane + i * 64]; s += vals[i]; }
#pragma unroll
    for (int off = 32; off > 0; off >>= 1) s += __shfl_xor(s, off, 64);
    float mean = s * (1.0f / D_);
    float vs = 0.f;
#pragma unroll
    for (int i = 0; i < 12; ++i) { float d = vals[i] - mean; vs += d * d; }
#pragma unroll
    for (int off = 32; off > 0; off >>= 1) vs += __shfl_xor(vs, off, 64);
    float rstd = rsqrtf(vs * (1.0f / D_) + EPSF);
    float* outr = out + (size_t)rowi * D_;
#pragma unroll
    for (int i = 0; i < 12; ++i) {
        int c = lane + i * 64;
        outr[c] = (vals[i] - mean) * rstd * w[c] + b[c];
    }
}

// ---------------- fp32 tiled GEMM, 64x64 tile, templated epilogue ----------------
enum { EPI_NONE = 0, EPI_RES = 1, EPI_GELU = 2 };

template <int EPI>
__global__ __launch_bounds__(256) void gemm_kernel(const float* __restrict__ A,
                                                   const float* __restrict__ Bm,
                                                   const float* __restrict__ bias,
                                                   const float* __restrict__ res,
                                                   float* __restrict__ C,
                                                   int M, int N, int K) {
    __shared__ float As[64][17];
    __shared__ float Bs[16][64];
    int tid = threadIdx.x;
    int tx = tid & 15, ty = tid >> 4;
    int row0 = blockIdx.y * 64;
    int col0 = blockIdx.x * 64;
    float acc[4][4] = {};
    int ar = tid >> 2, ac4 = tid & 3;   // A staging: row ar (0..63), cols ac4*4..+3
    int br = tid >> 4, bc4 = tid & 15;  // B staging: row br (0..15), cols bc4*4..+3
    const float* Ap = A + (size_t)(row0 + ar) * K + ac4 * 4;
    const float* Bp = Bm + (size_t)br * N + col0 + bc4 * 4;

    for (int k0 = 0; k0 < K; k0 += 16) {
        float4 av = *(const float4*)(Ap + k0);
        float4 bv = *(const float4*)(Bp + (size_t)k0 * N);
        As[ar][ac4 * 4 + 0] = av.x;
        As[ar][ac4 * 4 + 1] = av.y;
        As[ar][ac4 * 4 + 2] = av.z;
        As[ar][ac4 * 4 + 3] = av.w;
        *(float4*)&Bs[br][bc4 * 4] = bv;
        __syncthreads();
#pragma unroll
        for (int kk = 0; kk < 16; ++kk) {
            float a[4], bb[4];
#pragma unroll
            for (int i = 0; i < 4; ++i) a[i] = As[ty * 4 + i][kk];
#pragma unroll
            for (int j = 0; j < 4; ++j) bb[j] = Bs[kk][tx * 4 + j];
#pragma unroll
            for (int i = 0; i < 4; ++i)
#pragma unroll
                for (int j = 0; j < 4; ++j)
                    acc[i][j] = fmaf(a[i], bb[j], acc[i][j]);
        }
        __syncthreads();
    }
#pragma unroll
    for (int i = 0; i < 4; ++i) {
        int r = row0 + ty * 4 + i;
#pragma unroll
        for (int j = 0; j < 4; ++j) {
            int c = col0 + tx * 4 + j;
            float v = acc[i][j] + bias[c];
            if (EPI == EPI_GELU) v = 0.5f * v * (1.f + erff(v * 0.70710678118f));
            if (EPI == EPI_RES) v += res[(size_t)r * N + c];
            C[(size_t)r * N + c] = v;
        }
    }
}

// ---------------- fused attention: 4 q-rows per block ----------------
#define QT 4

__global__ __launch_bounds__(256) void attn_kernel(
    const float* __restrict__ qkv,
    const int* __restrict__ rowp, const int* __restrict__ colp,
    const int* __restrict__ drowp, const int* __restrict__ dcolp,
    const int* __restrict__ didp,
    const float* __restrict__ rel_emb, const float* __restrict__ demo_emb,
    float* __restrict__ attn_out) {
    __shared__ float s[QT][T_];          // 32 KB scores
    __shared__ float qs[QT][HD_];        // 1 KB
    __shared__ float red[QT];            // softmax denominators
    __shared__ float partial[4][QT][HD_]; // 4 KB split-K partials

    int bid = blockIdx.x;                 // ((b*H + h)*(T/QT) + qt)
    int qt = bid % (T_ / QT);
    int bh = bid / (T_ / QT);
    int h = bh % H_;
    int b = bh / H_;
    int q0 = qt * QT;
    int tid = threadIdx.x;

    // load q vectors into LDS
    {
        int qi = tid >> 6, d = tid & 63;  // 256 threads = QT*HD exactly
        qs[qi][d] = qkv[(size_t)(b * T_ + q0 + qi) * (3 * D_) + h * HD_ + d];
    }
    __syncthreads();

    int rq[QT], cq[QT], drq[QT], dcq[QT], idq[QT];
#pragma unroll
    for (int qi = 0; qi < QT; ++qi) {
        rq[qi] = rowp[q0 + qi];
        cq[qi] = colp[q0 + qi];
        drq[qi] = drowp[q0 + qi];
        dcq[qi] = dcolp[q0 + qi];
        idq[qi] = didp[q0 + qi];
    }
    const float scale = 0.125f;  // 1/sqrt(64)

    // ---- score pass: each thread handles 8 k rows ----
    for (int k = tid; k < T_; k += 256) {
        const float* kr = qkv + (size_t)(b * T_ + k) * (3 * D_) + D_ + h * HD_;
        float dot[QT] = {};
#pragma unroll
        for (int d4 = 0; d4 < HD_ / 4; ++d4) {
            float4 kv = *(const float4*)(kr + d4 * 4);
#pragma unroll
            for (int qi = 0; qi < QT; ++qi) {
                dot[qi] = fmaf(qs[qi][d4 * 4 + 0], kv.x, dot[qi]);
                dot[qi] = fmaf(qs[qi][d4 * 4 + 1], kv.y, dot[qi]);
                dot[qi] = fmaf(qs[qi][d4 * 4 + 2], kv.z, dot[qi]);
                dot[qi] = fmaf(qs[qi][d4 * 4 + 3], kv.w, dot[qi]);
            }
        }
        int rk = rowp[k], ck = colp[k], drk = drowp[k], dck = dcolp[k], idk = didp[k];
#pragma unroll
        for (int qi = 0; qi < QT; ++qi) {
            float bias = 0.f;
            // valid = !is_sep[q] && !is_sep[k]  ==  (demo_id >= 0) both sides
            if (idq[qi] >= 0 && idk >= 0) {
                int dr = min(max(rq[qi] - rk, -(G_ - 1)), G_ - 1) + (G_ - 1);
                int dc = min(max(cq[qi] - ck, -(G_ - 1)), G_ - 1) + (G_ - 1);
                bias = rel_emb[(size_t)(dr * SPAN_ + dc) * H_ + h];
                if (idq[qi] == idk) {
                    int ddr = min(max(drq[qi] - drk, -(G_ - 1)), G_ - 1) + (G_ - 1);
                    int ddc = min(max(dcq[qi] - dck, -2 * G_), 2 * G_) + 2 * G_;
                    bias += demo_emb[(size_t)(ddr * SPANC_ + ddc) * H_ + h];
                }
            }
            s[qi][k] = dot[qi] * scale + bias;
        }
    }
    __syncthreads();

    // ---- softmax: wave wv owns q-row wv ----
    {
        int wv = tid >> 6, lane = tid & 63;
        float m = -INFINITY;
        for (int k = lane; k < T_; k += 64) m = fmaxf(m, s[wv][k]);
#pragma unroll
        for (int off = 32; off > 0; off >>= 1) m = fmaxf(m, __shfl_xor(m, off, 64));
        float sum = 0.f;
        for (int k = lane; k < T_; k += 64) {
            float e = __expf(s[wv][k] - m);
            s[wv][k] = e;
            sum += e;
        }
#pragma unroll
        for (int off = 32; off > 0; off >>= 1) sum += __shfl_xor(sum, off, 64);
        if (lane == 0) red[wv] = sum;
    }
    __syncthreads();

    // ---- PV: thread (kg, d); kg = wave id, d = lane ----
    {
        int d = tid & 63, kg = tid >> 6;
        float acc[QT] = {};
        for (int k = kg * (T_ / 4); k < (kg + 1) * (T_ / 4); ++k) {
            float v = qkv[(size_t)(b * T_ + k) * (3 * D_) + 2 * D_ + h * HD_ + d];
#pragma unroll
            for (int qi = 0; qi < QT; ++qi) acc[qi] = fmaf(s[qi][k], v, acc[qi]);
        }
#pragma unroll
        for (int qi = 0; qi < QT; ++qi) partial[kg][qi][d] = acc[qi];
    }
    __syncthreads();
    {
        int d = tid & 63, qi = tid >> 6;
        float o = partial[0][qi][d] + partial[1][qi][d] + partial[2][qi][d] + partial[3][qi][d];
        o /= red[qi];
        attn_out[(size_t)(b * T_ + q0 + qi) * D_ + h * HD_ + d] = o;
    }
}

// ---------------- launcher ----------------
extern "C" void kernel_launch(void* const* d_in, const int* in_sizes, int n_in,
                              void* d_out, int out_size, void* d_ws, size_t ws_size,
                              hipStream_t stream) {
    const float* x = (const float*)d_in[0];
    const int* rowp = (const int*)d_in[1];
    const int* colp = (const int*)d_in[2];
    const int* drowp = (const int*)d_in[3];
    const int* dcolp = (const int*)d_in[4];
    const int* didp = (const int*)d_in[5];
    // d_in[6] = is_sep (bool) — unused: is_sep  <=>  demo_id < 0 by construction
    const float* ln1_w = (const float*)d_in[7];
    const float* ln1_b = (const float*)d_in[8];
    const float* ln2_w = (const float*)d_in[9];
    const float* ln2_b = (const float*)d_in[10];
    const float* qkv_w = (const float*)d_in[11];
    const float* qkv_b = (const float*)d_in[12];
    const float* proj_w = (const float*)d_in[13];
    const float* proj_b = (const float*)d_in[14];
    const float* ff1_w = (const float*)d_in[15];
    const float* ff1_b = (const float*)d_in[16];
    const float* ff2_w = (const float*)d_in[17];
    const float* ff2_b = (const float*)d_in[18];
    const float* rel_emb = (const float*)d_in[19];
    const float* demo_emb = (const float*)d_in[20];
    float* out = (float*)d_out;
    float* ws = (float*)d_ws;

    // workspace layout (floats):
    // R1: 12,582,912  — h1 (first 3.1M) -> attn_out (first 3.1M) -> ffact (all)
    // x2:  3,145,728  — residual stream after attention
    // R3:  9,437,184  — qkv -> h2 (first 3.1M)
    float* R1 = ws;
    float* x2 = R1 + 12582912;
    float* R3 = x2 + 3145728;
    float* h1 = R1;
    float* attn_o = R1;
    float* ffact = R1;
    float* qkvb = R3;
    float* h2 = R3;

    const int M = B_ * T_;  // 4096

    ln_kernel<<<dim3(M / 4), 256, 0, stream>>>(x, ln1_w, ln1_b, h1);

    gemm_kernel<EPI_NONE><<<dim3((3 * D_) / 64, M / 64), 256, 0, stream>>>(
        h1, qkv_w, qkv_b, nullptr, qkvb, M, 3 * D_, D_);

    attn_kernel<<<dim3(B_ * H_ * (T_ / QT)), 256, 0, stream>>>(
        qkvb, rowp, colp, drowp, dcolp, didp, rel_emb, demo_emb, attn_o);

    gemm_kernel<EPI_RES><<<dim3(D_ / 64, M / 64), 256, 0, stream>>>(
        attn_o, proj_w, proj_b, x, x2, M, D_, D_);

    ln_kernel<<<dim3(M / 4), 256, 0, stream>>>(x2, ln2_w, ln2_b, h2);

    gemm_kernel<EPI_GELU><<<dim3(FF_ / 64, M / 64), 256, 0, stream>>>(
        h2, ff1_w, ff1_b, nullptr, ffact, M, FF_, D_);

    gemm_kernel<EPI_RES><<<dim3(D_ / 64, M / 64), 256, 0, stream>>>(
        ffact, ff2_w, ff2_b, x2, out, M, D_, FF_);
}

// Round 3
// 527.019 us; speedup vs baseline: 7.3934x; 7.3934x over previous
//
#include <hip/hip_runtime.h>
#include <hip/hip_bf16.h>
#include <math.h>

#define G_ 32
#define H_ 12
#define D_ 768
#define HD_ 64
#define FF_ 3072
#define B_ 2
#define T_ 2048
#define SPAN_ 63
#define SPANC_ 129
#define EPSF 1e-5f

typedef short bf16x8 __attribute__((ext_vector_type(8)));
typedef short short4v __attribute__((ext_vector_type(4)));
typedef float f32x4 __attribute__((ext_vector_type(4)));

__device__ __forceinline__ short f2bf(float f) {
    unsigned u = __builtin_bit_cast(unsigned, f);
    u = u + 0x7FFFu + ((u >> 16) & 1u);
    return (short)(u >> 16);
}

// ---------------- LayerNorm (f32 in -> bf16 out): one wave per row ----------------
__global__ __launch_bounds__(256) void ln_bf16_kernel(const float* __restrict__ x,
                                                      const float* __restrict__ w,
                                                      const float* __restrict__ b,
                                                      short* __restrict__ out) {
    int wv = threadIdx.x >> 6;
    int lane = threadIdx.x & 63;
    int rowi = blockIdx.x * 4 + wv;
    const float* xr = x + (size_t)rowi * D_;
    float vals[12];
    float s = 0.f;
#pragma unroll
    for (int i = 0; i < 12; ++i) { vals[i] = xr[lane + i * 64]; s += vals[i]; }
#pragma unroll
    for (int off = 32; off > 0; off >>= 1) s += __shfl_xor(s, off, 64);
    float mean = s * (1.0f / D_);
    float vs = 0.f;
#pragma unroll
    for (int i = 0; i < 12; ++i) { float d = vals[i] - mean; vs += d * d; }
#pragma unroll
    for (int off = 32; off > 0; off >>= 1) vs += __shfl_xor(vs, off, 64);
    float rstd = rsqrtf(vs * (1.0f / D_) + EPSF);
    short* outr = out + (size_t)rowi * D_;
#pragma unroll
    for (int i = 0; i < 12; ++i) {
        int c = lane + i * 64;
        outr[c] = f2bf((vals[i] - mean) * rstd * w[c] + b[c]);
    }
}

// ---------------- transpose-cast: W [K][N] f32 -> Wt [N][K] bf16 ----------------
__global__ __launch_bounds__(256) void tcast_kernel(const float* __restrict__ W,
                                                    short* __restrict__ Wt,
                                                    int K, int N) {
    __shared__ float t[32][33];
    int n0 = blockIdx.x * 32, k0 = blockIdx.y * 32;
    int tid = threadIdx.x;
    int r = tid >> 3, c4 = (tid & 7) * 4;
    float4 v = *(const float4*)(W + (size_t)(k0 + r) * N + n0 + c4);
    t[r][c4 + 0] = v.x; t[r][c4 + 1] = v.y; t[r][c4 + 2] = v.z; t[r][c4 + 3] = v.w;
    __syncthreads();
    short4v o;
    o[0] = f2bf(t[c4 + 0][r]); o[1] = f2bf(t[c4 + 1][r]);
    o[2] = f2bf(t[c4 + 2][r]); o[3] = f2bf(t[c4 + 3][r]);
    *(short4v*)(Wt + (size_t)(n0 + r) * K + k0 + c4) = o;
}

// ---------------- bf16 MFMA GEMM: C = A[M][K] * Bt[N][K]^T ----------------
// 128x128 tile, BK=64, 4 waves (2x2), XOR-seg-swizzled LDS (T2).
enum { EPI_NONE = 0, EPI_RES = 1, EPI_GELU = 2 };

template <int EPI, int BF16OUT>
__global__ __launch_bounds__(256, 2) void gemm_bf16(const short* __restrict__ A,
                                                    const short* __restrict__ Bt,
                                                    const float* __restrict__ bias,
                                                    const float* __restrict__ res,
                                                    void* __restrict__ Cv,
                                                    int M, int N, int K) {
    __shared__ short As[128 * 64];
    __shared__ short Bs[128 * 64];
    int tid = threadIdx.x;
    int l = tid & 63;
    int w = tid >> 6;
    int wm = w >> 1, wn = w & 1;
    int row0 = blockIdx.y * 128, col0 = blockIdx.x * 128;
    int g = l >> 4, c16 = l & 15;
    f32x4 zero = {0.f, 0.f, 0.f, 0.f};
    f32x4 acc[4][4];
#pragma unroll
    for (int m = 0; m < 4; ++m)
#pragma unroll
        for (int n = 0; n < 4; ++n) acc[m][n] = zero;

    for (int k0 = 0; k0 < K; k0 += 64) {
#pragma unroll
        for (int p = 0; p < 4; ++p) {
            int sidx = p * 256 + tid;
            int row = sidx >> 3, cseg = sidx & 7;
            int ds = row * 64 + ((cseg ^ (row & 7)) << 3);
            *(bf16x8*)&As[ds] = *(const bf16x8*)(A + (size_t)(row0 + row) * K + k0 + cseg * 8);
            *(bf16x8*)&Bs[ds] = *(const bf16x8*)(Bt + (size_t)(col0 + row) * K + k0 + cseg * 8);
        }
        __syncthreads();
#pragma unroll
        for (int dk = 0; dk < 2; ++dk) {
            bf16x8 af[4], bfr[4];
#pragma unroll
            for (int m = 0; m < 4; ++m) {
                int r = wm * 64 + m * 16 + c16;
                af[m] = *(const bf16x8*)&As[r * 64 + (((dk * 4 + g) ^ (r & 7)) << 3)];
            }
#pragma unroll
            for (int n = 0; n < 4; ++n) {
                int r = wn * 64 + n * 16 + c16;
                bfr[n] = *(const bf16x8*)&Bs[r * 64 + (((dk * 4 + g) ^ (r & 7)) << 3)];
            }
#pragma unroll
            for (int m = 0; m < 4; ++m)
#pragma unroll
                for (int n = 0; n < 4; ++n)
                    acc[m][n] = __builtin_amdgcn_mfma_f32_16x16x32_bf16(af[m], bfr[n], acc[m][n], 0, 0, 0);
        }
        __syncthreads();
    }

#pragma unroll
    for (int m = 0; m < 4; ++m)
#pragma unroll
        for (int n = 0; n < 4; ++n) {
            int rrow = row0 + wm * 64 + m * 16 + g * 4;
            int ccol = col0 + wn * 64 + n * 16 + c16;
            float bv = bias[ccol];
#pragma unroll
            for (int i = 0; i < 4; ++i) {
                float v = acc[m][n][i] + bv;
                if (EPI == EPI_GELU) v = 0.5f * v * (1.f + erff(v * 0.70710678118f));
                if (EPI == EPI_RES) v += res[(size_t)(rrow + i) * N + ccol];
                if (BF16OUT)
                    ((short*)Cv)[(size_t)(rrow + i) * N + ccol] = f2bf(v);
                else
                    ((float*)Cv)[(size_t)(rrow + i) * N + ccol] = v;
            }
        }
}

// ---------------- fused MFMA flash attention with rel-pos bias ----------------
// Block: 256 thr (4 waves), QBLK=64 (wave w owns q-rows w*16..+15), KBLK=64.
__global__ __launch_bounds__(256, 2) void attn_mfma(
    const short* __restrict__ qkv,
    const int* __restrict__ rowp, const int* __restrict__ colp,
    const int* __restrict__ drowp, const int* __restrict__ dcolp,
    const int* __restrict__ didp,
    const float* __restrict__ rel_emb, const float* __restrict__ demo_emb,
    short* __restrict__ attn_o) {
    __shared__ short Ks[64 * 64];     // swizzled, like GEMM tiles
    __shared__ short Vt[64][72];      // V transposed [d][k], padded
    __shared__ short Pb[4][16 * 72];  // per-wave P re-layout buffer
    __shared__ int km[5][64];         // k-tile metadata

    int tid = threadIdx.x, w = tid >> 6, l = tid & 63;
    int g = l >> 4, c16 = l & 15;
    int qt = blockIdx.x & 31, bh = blockIdx.x >> 5;
    int h = bh % H_, b = bh / H_;
    int q0 = qt * 64;
    const int QS = 3 * D_;

    // Q fragments (A-operand: row = lane&15, k contiguous per 16-lane group)
    bf16x8 qf[2];
    {
        int qrow = q0 + w * 16 + c16;
        const short* qp = qkv + (size_t)(b * T_ + qrow) * QS + h * HD_;
#pragma unroll
        for (int dk = 0; dk < 2; ++dk) qf[dk] = *(const bf16x8*)(qp + dk * 32 + g * 8);
    }
    // q metadata for this lane's 4 C-layout rows (q = q0 + w*16 + g*4 + i)
    int mrq[4], mcq[4], mdrq[4], mdcq[4], midq[4];
#pragma unroll
    for (int i = 0; i < 4; ++i) {
        int qq = q0 + w * 16 + g * 4 + i;
        mrq[i] = rowp[qq]; mcq[i] = colp[qq]; mdrq[i] = drowp[qq];
        mdcq[i] = dcolp[qq]; midq[i] = didp[qq];
    }

    f32x4 zero = {0.f, 0.f, 0.f, 0.f};
    f32x4 oacc[4];
#pragma unroll
    for (int nf = 0; nf < 4; ++nf) oacc[nf] = zero;
    float mrun[4], lrun[4];
#pragma unroll
    for (int i = 0; i < 4; ++i) { mrun[i] = -INFINITY; lrun[i] = 0.f; }

    for (int kb = 0; kb < T_; kb += 64) {
        // ---- stage K (swizzled) ----
#pragma unroll
        for (int p = 0; p < 2; ++p) {
            int sidx = p * 256 + tid;
            int row = sidx >> 3, cseg = sidx & 7;
            *(bf16x8*)&Ks[row * 64 + ((cseg ^ (row & 7)) << 3)] =
                *(const bf16x8*)(qkv + (size_t)(b * T_ + kb + row) * QS + D_ + h * HD_ + cseg * 8);
        }
        // ---- stage V transposed ----
        {
            int vrow = tid >> 2, part = tid & 3;
            const short* vp = qkv + (size_t)(b * T_ + kb + vrow) * QS + 2 * D_ + h * HD_ + part * 16;
            bf16x8 v0 = *(const bf16x8*)(vp);
            bf16x8 v1 = *(const bf16x8*)(vp + 8);
#pragma unroll
            for (int j = 0; j < 8; ++j) Vt[part * 16 + j][vrow] = v0[j];
#pragma unroll
            for (int j = 0; j < 8; ++j) Vt[part * 16 + 8 + j][vrow] = v1[j];
        }
        // ---- stage k metadata ----
        if (tid < 64) {
            int kk = kb + tid;
            km[0][tid] = rowp[kk]; km[1][tid] = colp[kk]; km[2][tid] = drowp[kk];
            km[3][tid] = dcolp[kk]; km[4][tid] = didp[kk];
        }
        __syncthreads();

        // ---- QK^T ----
        f32x4 sac[4];
#pragma unroll
        for (int nf = 0; nf < 4; ++nf) sac[nf] = zero;
#pragma unroll
        for (int dk = 0; dk < 2; ++dk) {
#pragma unroll
            for (int nf = 0; nf < 4; ++nf) {
                int r = nf * 16 + c16;
                bf16x8 kf = *(const bf16x8*)&Ks[r * 64 + (((dk * 4 + g) ^ (r & 7)) << 3)];
                sac[nf] = __builtin_amdgcn_mfma_f32_16x16x32_bf16(qf[dk], kf, sac[nf], 0, 0, 0);
            }
        }

        // ---- bias + scale (lane holds S[q=g*4+i][k=nf*16+c16]) ----
        float st[4][4];
        float rmax[4] = {-INFINITY, -INFINITY, -INFINITY, -INFINITY};
#pragma unroll
        for (int nf = 0; nf < 4; ++nf) {
            int kk = nf * 16 + c16;
            int krow = km[0][kk], kcol = km[1][kk], kdr = km[2][kk], kdc = km[3][kk], kid = km[4][kk];
#pragma unroll
            for (int i = 0; i < 4; ++i) {
                float sv = sac[nf][i] * 0.125f;
                if (midq[i] >= 0 && kid >= 0) {
                    int dr = min(max(mrq[i] - krow, -(G_ - 1)), G_ - 1) + (G_ - 1);
                    int dc = min(max(mcq[i] - kcol, -(G_ - 1)), G_ - 1) + (G_ - 1);
                    sv += rel_emb[(dr * SPAN_ + dc) * H_ + h];
                    if (midq[i] == kid) {
                        int ddr = min(max(mdrq[i] - kdr, -(G_ - 1)), G_ - 1) + (G_ - 1);
                        int ddc = min(max(mdcq[i] - kdc, -2 * G_), 2 * G_) + 2 * G_;
                        sv += demo_emb[(ddr * SPANC_ + ddc) * H_ + h];
                    }
                }
                st[nf][i] = sv;
                rmax[i] = fmaxf(rmax[i], sv);
            }
        }
        // ---- online softmax (row spread across 16 lanes of same group) ----
#pragma unroll
        for (int i = 0; i < 4; ++i) {
#pragma unroll
            for (int off = 1; off < 16; off <<= 1)
                rmax[i] = fmaxf(rmax[i], __shfl_xor(rmax[i], off, 64));
        }
        float pp[4][4];
#pragma unroll
        for (int i = 0; i < 4; ++i) {
            float newm = fmaxf(mrun[i], rmax[i]);
            float sf = __expf(mrun[i] - newm);
            mrun[i] = newm;
            float ls = 0.f;
#pragma unroll
            for (int nf = 0; nf < 4; ++nf) {
                float e = __expf(st[nf][i] - newm);
                pp[nf][i] = e;
                ls += e;
            }
#pragma unroll
            for (int off = 1; off < 16; off <<= 1) ls += __shfl_xor(ls, off, 64);
            lrun[i] = lrun[i] * sf + ls;
#pragma unroll
            for (int nf = 0; nf < 4; ++nf) oacc[nf][i] *= sf;
        }
        // ---- P -> wave-private LDS (C-layout write, A-layout read) ----
        short* pbw = &Pb[w][0];
#pragma unroll
        for (int nf = 0; nf < 4; ++nf)
#pragma unroll
            for (int i = 0; i < 4; ++i)
                pbw[(g * 4 + i) * 72 + nf * 16 + c16] = f2bf(pp[nf][i]);
        // ---- PV ----
#pragma unroll
        for (int dk = 0; dk < 2; ++dk) {
            bf16x8 pa = *(const bf16x8*)&pbw[c16 * 72 + dk * 32 + g * 8];
#pragma unroll
            for (int nf = 0; nf < 4; ++nf) {
                bf16x8 vb = *(const bf16x8*)&Vt[nf * 16 + c16][dk * 32 + g * 8];
                oacc[nf] = __builtin_amdgcn_mfma_f32_16x16x32_bf16(pa, vb, oacc[nf], 0, 0, 0);
            }
        }
        __syncthreads();
    }

    // ---- finalize ----
#pragma unroll
    for (int nf = 0; nf < 4; ++nf)
#pragma unroll
        for (int i = 0; i < 4; ++i) {
            float o = oacc[nf][i] / lrun[i];
            int qq = q0 + w * 16 + g * 4 + i;
            attn_o[(size_t)(b * T_ + qq) * D_ + h * HD_ + nf * 16 + c16] = f2bf(o);
        }
}

// ---------------- launcher ----------------
extern "C" void kernel_launch(void* const* d_in, const int* in_sizes, int n_in,
                              void* d_out, int out_size, void* d_ws, size_t ws_size,
                              hipStream_t stream) {
    const float* x = (const float*)d_in[0];
    const int* rowp = (const int*)d_in[1];
    const int* colp = (const int*)d_in[2];
    const int* drowp = (const int*)d_in[3];
    const int* dcolp = (const int*)d_in[4];
    const int* didp = (const int*)d_in[5];
    // d_in[6] = is_sep (bool) — unused: is_sep <=> demo_id < 0 by construction
    const float* ln1_w = (const float*)d_in[7];
    const float* ln1_b = (const float*)d_in[8];
    const float* ln2_w = (const float*)d_in[9];
    const float* ln2_b = (const float*)d_in[10];
    const float* qkv_w = (const float*)d_in[11];
    const float* qkv_b = (const float*)d_in[12];
    const float* proj_w = (const float*)d_in[13];
    const float* proj_b = (const float*)d_in[14];
    const float* ff1_w = (const float*)d_in[15];
    const float* ff1_b = (const float*)d_in[16];
    const float* ff2_w = (const float*)d_in[17];
    const float* ff2_b = (const float*)d_in[18];
    const float* rel_emb = (const float*)d_in[19];
    const float* demo_emb = (const float*)d_in[20];
    float* out = (float*)d_out;

    const int M = B_ * T_;  // 4096
    char* p = (char*)d_ws;
    short* h1 = (short*)p;     p += (size_t)M * D_ * 2;
    short* qkvb = (short*)p;   p += (size_t)M * 3 * D_ * 2;
    short* attn_o = (short*)p; p += (size_t)M * D_ * 2;
    float* x2 = (float*)p;     p += (size_t)M * D_ * 4;
    short* h2 = (short*)p;     p += (size_t)M * D_ * 2;
    short* ffact = (short*)p;  p += (size_t)M * FF_ * 2;
    short* qkvt = (short*)p;   p += (size_t)(3 * D_) * D_ * 2;
    short* projt = (short*)p;  p += (size_t)D_ * D_ * 2;
    short* ff1t = (short*)p;   p += (size_t)FF_ * D_ * 2;
    short* ff2t = (short*)p;   p += (size_t)D_ * FF_ * 2;

    // weight transpose+cast (f32 [K][N] -> bf16 [N][K])
    tcast_kernel<<<dim3(3 * D_ / 32, D_ / 32), 256, 0, stream>>>(qkv_w, qkvt, D_, 3 * D_);
    tcast_kernel<<<dim3(D_ / 32, D_ / 32), 256, 0, stream>>>(proj_w, projt, D_, D_);
    tcast_kernel<<<dim3(FF_ / 32, D_ / 32), 256, 0, stream>>>(ff1_w, ff1t, D_, FF_);
    tcast_kernel<<<dim3(D_ / 32, FF_ / 32), 256, 0, stream>>>(ff2_w, ff2t, FF_, D_);

    ln_bf16_kernel<<<dim3(M / 4), 256, 0, stream>>>(x, ln1_w, ln1_b, h1);

    gemm_bf16<EPI_NONE, 1><<<dim3(3 * D_ / 128, M / 128), 256, 0, stream>>>(
        h1, qkvt, qkv_b, nullptr, qkvb, M, 3 * D_, D_);

    attn_mfma<<<dim3(B_ * H_ * (T_ / 64)), 256, 0, stream>>>(
        qkvb, rowp, colp, drowp, dcolp, didp, rel_emb, demo_emb, attn_o);

    gemm_bf16<EPI_RES, 0><<<dim3(D_ / 128, M / 128), 256, 0, stream>>>(
        attn_o, projt, proj_b, x, x2, M, D_, D_);

    ln_bf16_kernel<<<dim3(M / 4), 256, 0, stream>>>(x2, ln2_w, ln2_b, h2);

    gemm_bf16<EPI_GELU, 1><<<dim3(FF_ / 128, M / 128), 256, 0, stream>>>(
        h2, ff1t, ff1_b, nullptr, ffact, M, FF_, D_);

    gemm_bf16<EPI_RES, 0><<<dim3(D_ / 128, M / 128), 256, 0, stream>>>(
        ffact, ff2t, ff2_b, x2, out, M, D_, FF_);
}